// Round 11
// baseline (54.195 us; speedup 1.0000x reference)
//
#include <hip/hip_runtime.h>
#include <stdint.h>

// GGML Q8_0 fused dequant + GEMM:  out[16][8192] = x[16][8192] . W^T + bias
// HARNESS: quantized_weight arrives as int32, one GGML byte per element
// (zero-extended): 71,303,168 elems = 285.2 MB -> HBM-bound, ~45.3 us floor.
//
// R11 = R10 + WIDTH-16 global_load_lds staging (m97's +67% lever, R4 retry):
//   LDS row stride 1104 B = 69 exact 16-B units -> every per-lane global
//   source is 16-B aligned (R4's fault was the 1096-B stride's 8-mod-16
//   addresses). Staging: 18 slots x 1 KB per chunk (2-3 instrs/wave/round
//   vs 9 width-4). Quant ds_read_b64: dword idx 276c+34wv+2+8ksub -> 20c
//   mod 32, gcd 4 -> 8 bank-starts/16 lanes = 2-way aliasing = free (m136).
// x pre-converted to f16 (RTZ) in a pre-pass (R10 win, bit-identical).
// Dequant perm/xor/pk_add, mfma_f32_16x16x32_f16 + f32 scale fixup,
// double-buffered LDS, one __syncthreads per chunk, LDS cross-wave reduce.

typedef _Float16 half8   __attribute__((ext_vector_type(8)));
typedef _Float16 half2v  __attribute__((ext_vector_type(2)));
typedef float    float4v __attribute__((ext_vector_type(4)));
typedef uint2    __attribute__((may_alias)) u2a;
typedef uint4    __attribute__((may_alias)) u4a;
typedef float4v  __attribute__((may_alias)) f4a;

#define RSTRIDE_B 1104u   // LDS bytes per row image (1088 data + 16 pad)
#define UNITS_ROW 69u     // 16-B units per row (68 data + 1 pad)
#define CHUNK_DW  272     // global dwords per row per chunk (8 Q8 blocks)
#define BUFBYTES  18432u  // 18 slots * 1024 B

// two zero-extended quant bytes (.b0 of lo,hi) -> packed f16 pair == exact q
__device__ __forceinline__ uint32_t qpair(uint32_t lo, uint32_t hi) {
  uint32_t r = __builtin_amdgcn_perm(hi, lo, 0x0C040C00u); // [lo.b0,0,hi.b0,0]
  r ^= 0x64806480u;                                        // f16 1152+q each
  half2v v = __builtin_bit_cast(half2v, r);
  v = v + __builtin_bit_cast(half2v, (uint32_t)0xE480E480u); // -1152,-1152
  return __builtin_bit_cast(uint32_t, v);
}

__device__ __forceinline__ void gload16(const int* g, unsigned char* l) {
  __builtin_amdgcn_global_load_lds(
      (__attribute__((address_space(1))) void*)(void*)(const_cast<int*>(g)),
      (__attribute__((address_space(3))) void*)(void*)l,
      16, 0, 0);
}

// pre-pass: x f32 -> f16 (RTZ, identical numerics to inline cvt_pkrtz path)
extern "C" __global__ __launch_bounds__(256)
void xcvt_kernel(const float* __restrict__ x, _Float16* __restrict__ xh) {
  const int i = (blockIdx.x * 256 + threadIdx.x) * 8;   // 131072 elems total
  float4v f0 = *(const f4a*)(x + i);
  float4v f1 = *(const f4a*)(x + i + 4);
  uint4 o;
  o.x = __builtin_bit_cast(uint32_t, __builtin_amdgcn_cvt_pkrtz(f0[0], f0[1]));
  o.y = __builtin_bit_cast(uint32_t, __builtin_amdgcn_cvt_pkrtz(f0[2], f0[3]));
  o.z = __builtin_bit_cast(uint32_t, __builtin_amdgcn_cvt_pkrtz(f1[0], f1[1]));
  o.w = __builtin_bit_cast(uint32_t, __builtin_amdgcn_cvt_pkrtz(f1[2], f1[3]));
  *(u4a*)(xh + i) = o;
}

extern "C" __global__ __launch_bounds__(512, 4)
void q8lin_kernel(const _Float16* __restrict__ xh,
                  const int* __restrict__ wq,
                  const float* __restrict__ bias,
                  float* __restrict__ out)
{
  __shared__ __align__(16) unsigned char lds[2][BUFBYTES]; // 36 KB dbuf
  __shared__ __align__(16) float red[8][16][16];           // 8 KB

  const int tid  = threadIdx.x;
  const int wv   = tid >> 6;    // wave = chunk-local Q8 block index
  const int lane = tid & 63;
  const int c    = lane & 15;   // batch row (A) and weight row / out col (B)
  const int ksub = lane >> 4;   // k-subgroup within MFMA
  const int g    = blockIdx.x;  // output cols [g*16, g*16+16)

  // staging map: slot s -> 1 KB (64 units of 16 B); flat unit f = s*64+lane;
  // row r = f/69, in-row unit u = f-69r. Slots: wv, wv+8, (16+wv for wv<2).
  // Clamps only affect the global SOURCE (dup loads, benign); the LDS dest
  // is always the linear base+lane*16 (gload_lds contract).
  const int* gptr[3];
  unsigned   lofs[3];
#pragma unroll
  for (int t = 0; t < 3; ++t) {
    unsigned s = (t < 2) ? (unsigned)(wv + 8 * t) : (unsigned)(16 + wv);
    if (s > 17u) s = 17u;
    unsigned f = s * 64u + (unsigned)lane; if (f > 1103u) f = 1103u;
    unsigned r = f / UNITS_ROW;
    unsigned u = f - r * UNITS_ROW; if (u > 67u) u = 67u;  // skip pad unit
    gptr[t] = wq + (size_t)((unsigned)g * 16u + r) * 8704u + u * 4u;
    lofs[t] = s * 1024u;
  }
  const int nslot = (wv < 2) ? 3 : 2;

  const _Float16* xrow = xh + (size_t)c * 8192 + (unsigned)wv * 32u
                            + (unsigned)ksub * 8u;
  const unsigned rb = RSTRIDE_B * (unsigned)c + 136u * (unsigned)wv;
  const unsigned qb = rb + 8u + 32u * (unsigned)ksub;

  float4v acc = {0.f, 0.f, 0.f, 0.f};

  // prologue: chunk 0
  for (int t = 0; t < nslot; ++t) gload16(gptr[t], &lds[0][0] + lofs[t]);
  __syncthreads();   // compiler drains vmcnt before s_barrier

#pragma unroll 1
  for (int q = 0; q < 32; ++q) {
    const unsigned char* cur = &lds[q & 1][0];
    if (q < 31) {
      unsigned char* nxt = &lds[(q + 1) & 1][0];
      const int adv = (q + 1) * CHUNK_DW;   // 1088 B advance (16-B aligned)
      for (int t = 0; t < nslot; ++t) gload16(gptr[t] + adv, nxt + lofs[t]);
    }

    // scale: 2 int32 (bytes in .b0) at row byte 136*wv
    u2a s01 = *(const u2a*)(cur + rb);
    uint32_t sv = __builtin_amdgcn_perm(s01.y, s01.x, 0x0C0C0400u);
    const float dsc = (float)__builtin_bit_cast(_Float16, (uint16_t)sv);

    // quants: 8 int32 at row byte 136*wv + 8 + ksub*32 (2-way-aliased b64s)
    u2a d0 = *(const u2a*)(cur + qb);
    u2a d1 = *(const u2a*)(cur + qb + 8);
    u2a d2 = *(const u2a*)(cur + qb + 16);
    u2a d3 = *(const u2a*)(cur + qb + 24);
    half8 bfrag;
    { union { half8 h; uint32_t u[4]; } ub;
      ub.u[0] = qpair(d0.x, d0.y);
      ub.u[1] = qpair(d1.x, d1.y);
      ub.u[2] = qpair(d2.x, d2.y);
      ub.u[3] = qpair(d3.x, d3.y);
      bfrag = ub.h; }

    // A fragment: one 16-B load of pre-converted f16 x (L2-resident)
    half8 afrag = *(const half8*)(xrow + (size_t)q * 256);

    float4v D = __builtin_amdgcn_mfma_f32_16x16x32_f16(
        afrag, bfrag, (float4v){0.f, 0.f, 0.f, 0.f}, 0, 0, 0);
    acc[0] = fmaf(dsc, D[0], acc[0]);
    acc[1] = fmaf(dsc, D[1], acc[1]);
    acc[2] = fmaf(dsc, D[2], acc[2]);
    acc[3] = fmaf(dsc, D[3], acc[3]);

    __syncthreads();  // next buffer staged; cur free for overwrite
  }

  // cross-wave K-reduction. C/D layout (m89): col=lane&15, row=(lane>>4)*4+r
  *(f4a*)(&red[wv][c][ksub * 4]) = acc;
  __syncthreads();

  if (tid < 256) {
    const int cc = tid & 15;
    const int rr = tid >> 4;
    float s = bias[g * 16 + cc];
#pragma unroll
    for (int w = 0; w < 8; ++w) s += red[w][cc][rr];
    out[(size_t)rr * 8192 + (size_t)(g * 16 + cc)] = s;
  }
}

extern "C" void kernel_launch(void* const* d_in, const int* in_sizes, int n_in,
                              void* d_out, int out_size, void* d_ws, size_t ws_size,
                              hipStream_t stream) {
  const float* x    = (const float*)d_in[0];
  const int*   wq   = (const int*)d_in[1];
  const float* bias = (const float*)d_in[2];
  float*       out  = (float*)d_out;
  _Float16*    xh   = (_Float16*)d_ws;    // 16*8192*2 B = 256 KiB scratch
  (void)in_sizes; (void)n_in; (void)ws_size; (void)out_size;
  xcvt_kernel<<<dim3(64), dim3(256), 0, stream>>>(x, xh);
  q8lin_kernel<<<dim3(8192 / 16), dim3(512), 0, stream>>>(xh, wq, bias, out);
}